// Round 4
// baseline (395.274 us; speedup 1.0000x reference)
//
#include <hip/hip_runtime.h>
#include <hip/hip_bf16.h>
#include <stdint.h>

#define T_LEN 32768
#define DM 512
#define DH 512
#define NC 256          // number of scan chunks
#define CL 128          // chunk length  (NC*CL == T_LEN)

typedef __attribute__((ext_vector_type(8))) short short8;
typedef __attribute__((ext_vector_type(4))) float f32x4;

static __device__ __forceinline__ float b2f(__hip_bfloat16 v) { return __bfloat162float(v); }
static __device__ __forceinline__ __hip_bfloat16 f2b(float v) { return __float2bfloat16(v); }

static __device__ __forceinline__ void store_out(float* p, float v) { *p = v; }
static __device__ __forceinline__ void store_out(__hip_bfloat16* p, float v) { *p = f2b(v); }

// async global -> LDS, 16B per lane, dest = uniform base + lane*16
static __device__ __forceinline__ void load_lds16(const unsigned short* g, unsigned short* l) {
    __builtin_amdgcn_global_load_lds(
        (const __attribute__((address_space(1))) unsigned int*)g,
        (__attribute__((address_space(3))) unsigned int*)l, 16, 0, 0);
}

// start[] may arrive as int32 (0/1) or as 1-byte bools. Detect on device:
// int32 0/1 data read as u32 is never >1; byte bools (~50% ones) packed 4/word
// exceed 1 with certainty over 8192 words. All-zeros -> modes agree anyway.
__global__ void detect_start(const unsigned* __restrict__ s, int* __restrict__ flag) {
    int v = 0;
    for (int i = threadIdx.x; i < 8192; i += 64) v |= (s[i] > 1u) ? 1 : 0;
    unsigned long long b = __ballot(v);
    if (threadIdx.x == 0) *flag = (b != 0ull) ? 1 : 0;
}

static __device__ __forceinline__ int get_start(const int* start, int mode, int t) {
    return mode ? (int)((const unsigned char*)start)[t] : start[t];
}

// ---------------------------------------------------------------------------
// prep kernels (fp32 inputs -> bf16 GEMM operands)
// ---------------------------------------------------------------------------
__global__ void prep_x(const float* __restrict__ x, __hip_bfloat16* __restrict__ xb) {
    int i = (blockIdx.x * 256 + threadIdx.x) * 4;     // total 16,777,216 elements
    float4 v = *(const float4*)(x + i);
    xb[i + 0] = f2b(v.x);
    xb[i + 1] = f2b(v.y);
    xb[i + 2] = f2b(v.z);
    xb[i + 3] = f2b(v.w);
}

// B1: (1024 x 512)  rows 0..511 = B_re[h,:]*exp(gamma_log[h]), rows 512..1023 = B_im*exp(gamma)
__global__ void prep_B1(const float* __restrict__ B_re,
                        const float* __restrict__ B_im,
                        const float* __restrict__ gamma_log,
                        __hip_bfloat16* __restrict__ B1) {
    int idx = blockIdx.x * 256 + threadIdx.x;   // 0 .. 1024*512-1
    int row = idx >> 9;
    int m   = idx & 511;
    int h   = row & 511;
    float g = expf(gamma_log[h]);
    float v = (row < 512) ? B_re[(size_t)h * 512 + m] : B_im[(size_t)h * 512 + m];
    B1[idx] = f2b(v * g);
}

// B2: (512 x 1024)  cols 0..511 = C_re[m,:],  cols 512..1023 = -C_im[m,:]
__global__ void prep_B2(const float* __restrict__ C_re,
                        const float* __restrict__ C_im,
                        __hip_bfloat16* __restrict__ B2) {
    int idx = blockIdx.x * 256 + threadIdx.x;   // 0 .. 512*1024-1
    int m = idx >> 10;
    int k = idx & 1023;
    float v = (k < 512) ? C_re[(size_t)m * 512 + k]
                        : -C_im[(size_t)m * 512 + (k - 512)];
    B2[idx] = f2b(v);
}

// ---------------------------------------------------------------------------
// GEMM: Out[m][n] = sum_k A[m][k] * B[n][k]   (A: M x K, B: N x K, bf16)
// 128x128 tile, BK=64, 4 waves, mfma_f32_16x16x32_bf16, global_load_lds staging
// optional epilogue: + xres[m][n] * Dv[n]   (fp32, used by GEMM2)
// ---------------------------------------------------------------------------
template <int KDIM, typename OutT>
__global__ void gemm_bt(const __hip_bfloat16* __restrict__ A,
                        const __hip_bfloat16* __restrict__ B,
                        OutT* __restrict__ out, int ldc,
                        const float* __restrict__ xres,
                        const float* __restrict__ Dv) {
    __shared__ unsigned short As[128 * 64];
    __shared__ unsigned short Bs[128 * 64];
    const int lane = threadIdx.x & 63;
    const int wave = threadIdx.x >> 6;
    const int bx = blockIdx.x;          // col tile (N/128)
    const int by = blockIdx.y;          // row tile (M/128)
    const int wm = (wave >> 1) * 64;
    const int wn = (wave & 1) * 64;
    const int lrow = lane >> 3;         // 0..7
    const int lcol = (lane & 7) * 8;    // 0..56

    const unsigned short* Au = (const unsigned short*)A;
    const unsigned short* Bu = (const unsigned short*)B;

    f32x4 acc[4][4] = {};

    for (int kt = 0; kt < KDIM / 64; ++kt) {
        const int k0 = kt * 64;
#pragma unroll
        for (int j = 0; j < 4; ++j) {
            int ii = wave * 4 + j;              // 0..15, 8 rows per instruction
            int row = ii * 8 + lrow;
            load_lds16(Au + (size_t)(by * 128 + row) * KDIM + k0 + lcol, &As[ii * 512]);
            load_lds16(Bu + (size_t)(bx * 128 + row) * KDIM + k0 + lcol, &Bs[ii * 512]);
        }
        __syncthreads();
#pragma unroll
        for (int ks = 0; ks < 2; ++ks) {
            short8 af[4], bfr[4];
#pragma unroll
            for (int i = 0; i < 4; ++i) {
                af[i]  = *(const short8*)&As[(wm + i * 16 + (lane & 15)) * 64 + ks * 32 + (lane >> 4) * 8];
                bfr[i] = *(const short8*)&Bs[(wn + i * 16 + (lane & 15)) * 64 + ks * 32 + (lane >> 4) * 8];
            }
#pragma unroll
            for (int i = 0; i < 4; ++i)
#pragma unroll
                for (int j = 0; j < 4; ++j)
                    acc[i][j] = __builtin_amdgcn_mfma_f32_16x16x32_bf16(af[i], bfr[j], acc[i][j], 0, 0, 0);
        }
        __syncthreads();
    }

    // epilogue: C/D layout col=lane&15, row=(lane>>4)*4+r
    const int rowq = (lane >> 4) * 4;
#pragma unroll
    for (int i = 0; i < 4; ++i) {
#pragma unroll
        for (int r = 0; r < 4; ++r) {
            int row = by * 128 + wm + i * 16 + rowq + r;
#pragma unroll
            for (int j = 0; j < 4; ++j) {
                int col = bx * 128 + wn + j * 16 + (lane & 15);
                float v = acc[i][j][r];
                if (xres) v += xres[(size_t)row * DM + col] * Dv[col];
                store_out(&out[(size_t)row * ldc + col], v);
            }
        }
    }
}

// ---------------------------------------------------------------------------
// Segmented scan, 3 phases. Bu layout: row t = [re(0..511) | im(512..1023)] bf16.
// h_t = lambda*(start_t ? 0 : h_{t-1}) + Bu_t  (complex per channel), h_{-1}=state
// Phase 3 overwrites Bu in place with xs.
// ---------------------------------------------------------------------------
static __device__ __forceinline__ void get_lambda(const float* nu_log,
                                                  const float* theta_log,
                                                  int h, float& lr, float& li) {
    float nu = expf(nu_log[h]);
    float th = expf(theta_log[h]);
    float mag = expf(-nu);
    lr = mag * cosf(th);
    li = mag * sinf(th);
}

__global__ void scan_phase1(const __hip_bfloat16* __restrict__ Bu,
                            const int* __restrict__ start,
                            const int* __restrict__ smode,
                            const float* __restrict__ nu_log,
                            const float* __restrict__ theta_log,
                            float4* __restrict__ agg) {
    const int h = threadIdx.x;      // 0..511
    const int c = blockIdx.x;       // 0..NC-1
    const int mode = *smode;
    float lr, li;
    get_lambda(nu_log, theta_log, h, lr, li);
    float ar = 1.f, ai = 0.f, br = 0.f, bi = 0.f;
    const int t0 = c * CL;
#pragma unroll 4
    for (int i = 0; i < CL; ++i) {
        int t = t0 + i;
        float s = get_start(start, mode, t) ? 0.f : 1.f;
        float slr = lr * s, sli = li * s;
        float bur = b2f(Bu[(size_t)t * 1024 + h]);
        float bui = b2f(Bu[(size_t)t * 1024 + 512 + h]);
        float nar = slr * ar - sli * ai;
        float nai = slr * ai + sli * ar;
        float nbr = slr * br - sli * bi + bur;
        float nbi = slr * bi + sli * br + bui;
        ar = nar; ai = nai; br = nbr; bi = nbi;
    }
    agg[(size_t)c * DH + h] = make_float4(ar, ai, br, bi);
}

__global__ void scan_phase2(const float4* __restrict__ agg,
                            const float* __restrict__ state,
                            float2* __restrict__ prefix) {
    const int h = blockIdx.x * blockDim.x + threadIdx.x;   // 0..511
    float hr = state[h];
    float hi = 0.f;
    for (int c = 0; c < NC; ++c) {
        prefix[(size_t)c * DH + h] = make_float2(hr, hi);
        float4 a = agg[(size_t)c * DH + h];
        float nr = a.x * hr - a.y * hi + a.z;
        float ni = a.x * hi + a.y * hr + a.w;
        hr = nr; hi = ni;
    }
}

__global__ void scan_phase3(__hip_bfloat16* __restrict__ Bu,   // in: Bu, out: xs (in place)
                            const int* __restrict__ start,
                            const int* __restrict__ smode,
                            const float* __restrict__ nu_log,
                            const float* __restrict__ theta_log,
                            const float2* __restrict__ prefix,
                            float* __restrict__ dstate, int interleaved) {
    const int h = threadIdx.x;
    const int c = blockIdx.x;
    const int mode = *smode;
    float lr, li;
    get_lambda(nu_log, theta_log, h, lr, li);
    float2 p = prefix[(size_t)c * DH + h];
    float hr = p.x, hi = p.y;
    const int t0 = c * CL;
#pragma unroll 4
    for (int i = 0; i < CL; ++i) {
        int t = t0 + i;
        float s = get_start(start, mode, t) ? 0.f : 1.f;
        float slr = lr * s, sli = li * s;
        float bur = b2f(Bu[(size_t)t * 1024 + h]);
        float bui = b2f(Bu[(size_t)t * 1024 + 512 + h]);
        float nhr = slr * hr - sli * hi + bur;
        float nhi = slr * hi + sli * hr + bui;
        hr = nhr; hi = nhi;
        Bu[(size_t)t * 1024 + h] = f2b(hr);
        Bu[(size_t)t * 1024 + 512 + h] = f2b(hi);
    }
    if (c == NC - 1) {              // final state
        if (interleaved) {          // complex64 flat view: (re, im) pairs
            dstate[2 * h]     = hr;
            dstate[2 * h + 1] = hi;
        } else {                    // unsafe-cast to fp32: real part only
            dstate[h] = hr;
        }
    }
}

// ---------------------------------------------------------------------------
extern "C" void kernel_launch(void* const* d_in, const int* in_sizes, int n_in,
                              void* d_out, int out_size, void* d_ws, size_t ws_size,
                              hipStream_t stream) {
    const float* state = (const float*)d_in[0];
    const float* x     = (const float*)d_in[1];
    const int*   start = (const int*)d_in[2];
    const float* theta = (const float*)d_in[3];
    const float* nu    = (const float*)d_in[4];
    const float* gam   = (const float*)d_in[5];
    const float* B_re  = (const float*)d_in[6];
    const float* B_im  = (const float*)d_in[7];
    const float* C_re  = (const float*)d_in[8];
    const float* C_im  = (const float*)d_in[9];
    const float* Dv    = (const float*)d_in[10];
    float* out = (float*)d_out;

    // output-0 layout: ref output 0 is complex64 (1,512).
    // out_size - T*DM == 1024 -> stored as interleaved fp32 pairs;
    // == 512 -> unsafe-cast kept real part only. Deterministic per problem.
    const long long t_dm = (long long)T_LEN * DM;
    int state_floats = (int)((long long)out_size - t_dm);
    int interleaved = (state_floats >= 1024) ? 1 : 0;
    if (state_floats < 512) state_floats = 512;   // safety fallback

    // workspace layout (~101 MB total)
    char* ws = (char*)d_ws;
    __hip_bfloat16* xb = (__hip_bfloat16*)(ws);                     // 32 MB (T x 512 bf16)
    __hip_bfloat16* B1 = (__hip_bfloat16*)(ws + (32ll << 20));      // 1 MB  (1024x512)
    __hip_bfloat16* B2 = (__hip_bfloat16*)(ws + (33ll << 20));      // 1 MB  (512x1024)
    __hip_bfloat16* Bu = (__hip_bfloat16*)(ws + (34ll << 20));      // 64 MB (T x 1024), becomes xs in place
    float4* agg        = (float4*)(ws + (98ll << 20));              // 2 MB
    float2* pre        = (float2*)(ws + (100ll << 20));             // 1 MB
    int* smode         = (int*)(ws + (101ll << 20));                // 4 B

    detect_start<<<1, 64, 0, stream>>>((const unsigned*)start, smode);
    prep_x <<<16384, 256, 0, stream>>>(x, xb);
    prep_B1<<<2048, 256, 0, stream>>>(B_re, B_im, gam, B1);
    prep_B2<<<2048, 256, 0, stream>>>(C_re, C_im, B2);
    // GEMM1: Bu = xb @ B1^T   (M=32768, N=1024, K=512)
    gemm_bt<512, __hip_bfloat16><<<dim3(8, 256), 256, 0, stream>>>(xb, B1, Bu, 1024, nullptr, nullptr);
    scan_phase1<<<NC, 512, 0, stream>>>(Bu, start, smode, nu, theta, agg);
    scan_phase2<<<2, 256, 0, stream>>>(agg, state, pre);
    scan_phase3<<<NC, 512, 0, stream>>>(Bu, start, smode, nu, theta, pre, out, interleaved);
    // GEMM2: outputs = [xs_re|xs_im] @ [C_re|-C_im]^T + x*D   (M=32768, N=512, K=1024), fp32 out
    gemm_bt<1024, float><<<dim3(4, 256), 256, 0, stream>>>(Bu, B2, out + state_floats, 512, x, Dv);
}

// Round 5
// 388.319 us; speedup vs baseline: 1.0179x; 1.0179x over previous
//
#include <hip/hip_runtime.h>
#include <hip/hip_bf16.h>
#include <stdint.h>

#define T_LEN 32768
#define DM 512
#define DH 512
#define NC 256          // number of scan chunks
#define CL 128          // chunk length  (NC*CL == T_LEN)

typedef __attribute__((ext_vector_type(8))) short short8;
typedef __attribute__((ext_vector_type(4))) float f32x4;

static __device__ __forceinline__ float b2f(__hip_bfloat16 v) { return __bfloat162float(v); }
static __device__ __forceinline__ __hip_bfloat16 f2b(float v) { return __float2bfloat16(v); }

static __device__ __forceinline__ void store_out(float* p, float v) { *p = v; }
static __device__ __forceinline__ void store_out(__hip_bfloat16* p, float v) { *p = f2b(v); }

// packed (re,im) bf16 pair helpers: lo 16 bits = re, hi 16 bits = im
static __device__ __forceinline__ float bflo(unsigned u) { return __uint_as_float(u << 16); }
static __device__ __forceinline__ float bfhi(unsigned u) { return __uint_as_float(u & 0xffff0000u); }
static __device__ __forceinline__ unsigned packbf2(float re, float im) {
    union { __hip_bfloat16 h; unsigned short s; } a, b;
    a.h = f2b(re); b.h = f2b(im);
    return (unsigned)a.s | ((unsigned)b.s << 16);
}

// async global -> LDS, 16B per lane, dest = uniform base + lane*16
static __device__ __forceinline__ void load_lds16(const unsigned short* g, unsigned short* l) {
    __builtin_amdgcn_global_load_lds(
        (const __attribute__((address_space(1))) unsigned int*)g,
        (__attribute__((address_space(3))) unsigned int*)l, 16, 0, 0);
}

// start[] may arrive as int32 (0/1) or as 1-byte bools. Detect on device.
__global__ void detect_start(const unsigned* __restrict__ s, int* __restrict__ flag) {
    int v = 0;
    for (int i = threadIdx.x; i < 8192; i += 64) v |= (s[i] > 1u) ? 1 : 0;
    unsigned long long b = __ballot(v);
    if (threadIdx.x == 0) *flag = (b != 0ull) ? 1 : 0;
}

static __device__ __forceinline__ int get_start(const int* start, int mode, int t) {
    return mode ? (int)((const unsigned char*)start)[t] : start[t];
}

// ---------------------------------------------------------------------------
// prep kernels (fp32 inputs -> bf16 GEMM operands)
// ---------------------------------------------------------------------------
__global__ void prep_x(const float* __restrict__ x, __hip_bfloat16* __restrict__ xb) {
    int i = (blockIdx.x * 256 + threadIdx.x) * 4;     // total 16,777,216 elements
    float4 v = *(const float4*)(x + i);
    xb[i + 0] = f2b(v.x);
    xb[i + 1] = f2b(v.y);
    xb[i + 2] = f2b(v.z);
    xb[i + 3] = f2b(v.w);
}

// B1: (1024 x 512)  row 2h = B_re[h,:]*exp(gamma[h]), row 2h+1 = B_im[h,:]*exp(gamma[h])
// -> Bu columns come out (re,im)-interleaved per channel
__global__ void prep_B1(const float* __restrict__ B_re,
                        const float* __restrict__ B_im,
                        const float* __restrict__ gamma_log,
                        __hip_bfloat16* __restrict__ B1) {
    int idx = blockIdx.x * 256 + threadIdx.x;   // 0 .. 1024*512-1
    int row = idx >> 9;
    int m   = idx & 511;
    int h   = row >> 1;
    float g = expf(gamma_log[h]);
    float v = (row & 1) ? B_im[(size_t)h * 512 + m] : B_re[(size_t)h * 512 + m];
    B1[idx] = f2b(v * g);
}

// B2: (512 x 1024)  col 2h = C_re[m,h], col 2h+1 = -C_im[m,h]  (matches interleaved xs)
__global__ void prep_B2(const float* __restrict__ C_re,
                        const float* __restrict__ C_im,
                        __hip_bfloat16* __restrict__ B2) {
    int idx = blockIdx.x * 256 + threadIdx.x;   // 0 .. 512*1024-1
    int m = idx >> 10;
    int k = idx & 1023;
    int h = k >> 1;
    float v = (k & 1) ? -C_im[(size_t)m * 512 + h]
                      :  C_re[(size_t)m * 512 + h];
    B2[idx] = f2b(v);
}

// ---------------------------------------------------------------------------
// GEMM: Out[m][n] = sum_k A[m][k] * B[n][k]   (A: M x K, B: N x K, bf16)
// 128x128 tile, BK=64, 4 waves, mfma_f32_16x16x32_bf16, global_load_lds staging.
// Grid: (M/128, N/128) with by = blockIdx.x (FAST dim) so the N/128 blocks
// sharing an A-row-tile differ by gridDim.x in linear id -> same XCD (id%8)
// -> A-tile fetched from HBM once per XCD group, held in that XCD's L2.
// optional epilogue: + xres[m][n] * Dv[n]  (xres bf16, Dv fp32; used by GEMM2)
// ---------------------------------------------------------------------------
template <int KDIM, typename OutT>
__global__ void gemm_bt(const __hip_bfloat16* __restrict__ A,
                        const __hip_bfloat16* __restrict__ B,
                        OutT* __restrict__ out, int ldc,
                        const __hip_bfloat16* __restrict__ xres,
                        const float* __restrict__ Dv) {
    __shared__ unsigned short As[128 * 64];
    __shared__ unsigned short Bs[128 * 64];
    const int lane = threadIdx.x & 63;
    const int wave = threadIdx.x >> 6;
    const int by = blockIdx.x;          // row tile (M/128)  -- fast dim
    const int bx = blockIdx.y;          // col tile (N/128)
    const int wm = (wave >> 1) * 64;
    const int wn = (wave & 1) * 64;
    const int lrow = lane >> 3;         // 0..7
    const int lcol = (lane & 7) * 8;    // 0..56

    const unsigned short* Au = (const unsigned short*)A;
    const unsigned short* Bu = (const unsigned short*)B;

    f32x4 acc[4][4] = {};

    for (int kt = 0; kt < KDIM / 64; ++kt) {
        const int k0 = kt * 64;
#pragma unroll
        for (int j = 0; j < 4; ++j) {
            int ii = wave * 4 + j;              // 0..15, 8 rows per instruction
            int row = ii * 8 + lrow;
            load_lds16(Au + (size_t)(by * 128 + row) * KDIM + k0 + lcol, &As[ii * 512]);
            load_lds16(Bu + (size_t)(bx * 128 + row) * KDIM + k0 + lcol, &Bs[ii * 512]);
        }
        __syncthreads();
#pragma unroll
        for (int ks = 0; ks < 2; ++ks) {
            short8 af[4], bfr[4];
#pragma unroll
            for (int i = 0; i < 4; ++i) {
                af[i]  = *(const short8*)&As[(wm + i * 16 + (lane & 15)) * 64 + ks * 32 + (lane >> 4) * 8];
                bfr[i] = *(const short8*)&Bs[(wn + i * 16 + (lane & 15)) * 64 + ks * 32 + (lane >> 4) * 8];
            }
#pragma unroll
            for (int i = 0; i < 4; ++i)
#pragma unroll
                for (int j = 0; j < 4; ++j)
                    acc[i][j] = __builtin_amdgcn_mfma_f32_16x16x32_bf16(af[i], bfr[j], acc[i][j], 0, 0, 0);
        }
        __syncthreads();
    }

    // epilogue: C/D layout col=lane&15, row=(lane>>4)*4+r
    const int rowq = (lane >> 4) * 4;
#pragma unroll
    for (int i = 0; i < 4; ++i) {
#pragma unroll
        for (int r = 0; r < 4; ++r) {
            int row = by * 128 + wm + i * 16 + rowq + r;
#pragma unroll
            for (int j = 0; j < 4; ++j) {
                int col = bx * 128 + wn + j * 16 + (lane & 15);
                float v = acc[i][j][r];
                if (xres) v += b2f(xres[(size_t)row * DM + col]) * Dv[col];
                store_out(&out[(size_t)row * ldc + col], v);
            }
        }
    }
}

// ---------------------------------------------------------------------------
// Segmented scan, 3 phases. Bu layout: row t = 512 packed uints, uint h =
// (re,im) bf16 pair of channel h.  h_t = lambda*(start_t?0:h_{t-1}) + Bu_t.
// Phase 3 overwrites Bu in place with xs (same interleaved layout).
// ---------------------------------------------------------------------------
static __device__ __forceinline__ void get_lambda(const float* nu_log,
                                                  const float* theta_log,
                                                  int h, float& lr, float& li) {
    float nu = expf(nu_log[h]);
    float th = expf(theta_log[h]);
    float mag = expf(-nu);
    lr = mag * cosf(th);
    li = mag * sinf(th);
}

__global__ void scan_phase1(const unsigned* __restrict__ Bu,
                            const int* __restrict__ start,
                            const int* __restrict__ smode,
                            const float* __restrict__ nu_log,
                            const float* __restrict__ theta_log,
                            float4* __restrict__ agg) {
    const int h = threadIdx.x;      // 0..511
    const int c = blockIdx.x;       // 0..NC-1
    const int mode = *smode;
    float lr, li;
    get_lambda(nu_log, theta_log, h, lr, li);
    float ar = 1.f, ai = 0.f, br = 0.f, bi = 0.f;
    const int t0 = c * CL;
#pragma unroll 4
    for (int i = 0; i < CL; ++i) {
        int t = t0 + i;
        float s = get_start(start, mode, t) ? 0.f : 1.f;
        float slr = lr * s, sli = li * s;
        unsigned u = Bu[(size_t)t * 512 + h];
        float bur = bflo(u), bui = bfhi(u);
        float nar = slr * ar - sli * ai;
        float nai = slr * ai + sli * ar;
        float nbr = slr * br - sli * bi + bur;
        float nbi = slr * bi + sli * br + bui;
        ar = nar; ai = nai; br = nbr; bi = nbi;
    }
    agg[(size_t)c * DH + h] = make_float4(ar, ai, br, bi);
}

__global__ void scan_phase2(const float4* __restrict__ agg,
                            const float* __restrict__ state,
                            float2* __restrict__ prefix) {
    const int h = blockIdx.x * blockDim.x + threadIdx.x;   // 0..511
    float hr = state[h];
    float hi = 0.f;
#pragma unroll 8
    for (int c = 0; c < NC; ++c) {
        prefix[(size_t)c * DH + h] = make_float2(hr, hi);
        float4 a = agg[(size_t)c * DH + h];
        float nr = a.x * hr - a.y * hi + a.z;
        float ni = a.x * hi + a.y * hr + a.w;
        hr = nr; hi = ni;
    }
}

__global__ void scan_phase3(unsigned* __restrict__ Bu,   // in: Bu, out: xs (in place)
                            const int* __restrict__ start,
                            const int* __restrict__ smode,
                            const float* __restrict__ nu_log,
                            const float* __restrict__ theta_log,
                            const float2* __restrict__ prefix,
                            float* __restrict__ dstate, int interleaved) {
    const int h = threadIdx.x;
    const int c = blockIdx.x;
    const int mode = *smode;
    float lr, li;
    get_lambda(nu_log, theta_log, h, lr, li);
    float2 p = prefix[(size_t)c * DH + h];
    float hr = p.x, hi = p.y;
    const int t0 = c * CL;
#pragma unroll 4
    for (int i = 0; i < CL; ++i) {
        int t = t0 + i;
        float s = get_start(start, mode, t) ? 0.f : 1.f;
        float slr = lr * s, sli = li * s;
        unsigned u = Bu[(size_t)t * 512 + h];
        float bur = bflo(u), bui = bfhi(u);
        float nhr = slr * hr - sli * hi + bur;
        float nhi = slr * hi + sli * hr + bui;
        hr = nhr; hi = nhi;
        Bu[(size_t)t * 512 + h] = packbf2(hr, hi);
    }
    if (c == NC - 1) {              // final state
        if (interleaved) {          // complex64 flat view: (re, im) pairs
            dstate[2 * h]     = hr;
            dstate[2 * h + 1] = hi;
        } else {                    // unsafe-cast to fp32: real part only
            dstate[h] = hr;
        }
    }
}

// ---------------------------------------------------------------------------
extern "C" void kernel_launch(void* const* d_in, const int* in_sizes, int n_in,
                              void* d_out, int out_size, void* d_ws, size_t ws_size,
                              hipStream_t stream) {
    const float* state = (const float*)d_in[0];
    const float* x     = (const float*)d_in[1];
    const int*   start = (const int*)d_in[2];
    const float* theta = (const float*)d_in[3];
    const float* nu    = (const float*)d_in[4];
    const float* gam   = (const float*)d_in[5];
    const float* B_re  = (const float*)d_in[6];
    const float* B_im  = (const float*)d_in[7];
    const float* C_re  = (const float*)d_in[8];
    const float* C_im  = (const float*)d_in[9];
    const float* Dv    = (const float*)d_in[10];
    float* out = (float*)d_out;

    const long long t_dm = (long long)T_LEN * DM;
    int state_floats = (int)((long long)out_size - t_dm);
    int interleaved = (state_floats >= 1024) ? 1 : 0;
    if (state_floats < 512) state_floats = 512;   // safety fallback

    // workspace layout (~101 MB total)
    char* ws = (char*)d_ws;
    __hip_bfloat16* xb = (__hip_bfloat16*)(ws);                     // 32 MB (T x 512 bf16)
    __hip_bfloat16* B1 = (__hip_bfloat16*)(ws + (32ll << 20));      // 1 MB  (1024x512)
    __hip_bfloat16* B2 = (__hip_bfloat16*)(ws + (33ll << 20));      // 1 MB  (512x1024)
    __hip_bfloat16* Bu = (__hip_bfloat16*)(ws + (34ll << 20));      // 64 MB (T x 1024), becomes xs in place
    float4* agg        = (float4*)(ws + (98ll << 20));              // 2 MB
    float2* pre        = (float2*)(ws + (100ll << 20));             // 1 MB
    int* smode         = (int*)(ws + (101ll << 20));                // 4 B

    detect_start<<<1, 64, 0, stream>>>((const unsigned*)start, smode);
    prep_x <<<16384, 256, 0, stream>>>(x, xb);
    prep_B1<<<2048, 256, 0, stream>>>(B_re, B_im, gam, B1);
    prep_B2<<<2048, 256, 0, stream>>>(C_re, C_im, B2);
    // GEMM1: Bu = xb @ B1^T   (M=32768, N=1024, K=512), by fast for XCD/L2 reuse
    gemm_bt<512, __hip_bfloat16><<<dim3(256, 8), 256, 0, stream>>>(xb, B1, Bu, 1024, nullptr, nullptr);
    scan_phase1<<<NC, 512, 0, stream>>>((const unsigned*)Bu, start, smode, nu, theta, agg);
    scan_phase2<<<2, 256, 0, stream>>>(agg, state, pre);
    scan_phase3<<<NC, 512, 0, stream>>>((unsigned*)Bu, start, smode, nu, theta, pre, out, interleaved);
    // GEMM2: outputs = xs @ B2^T + x*D   (M=32768, N=512, K=1024), fp32 out
    gemm_bt<1024, float><<<dim3(256, 4), 256, 0, stream>>>(Bu, B2, out + state_floats, 512, xb, Dv);
}

// Round 6
// 358.695 us; speedup vs baseline: 1.1020x; 1.0826x over previous
//
#include <hip/hip_runtime.h>
#include <hip/hip_bf16.h>
#include <stdint.h>

#define T_LEN 32768
#define DM 512
#define DH 512
#define NC 512          // number of scan chunks
#define CL 64           // chunk length  (NC*CL == T_LEN)

typedef __attribute__((ext_vector_type(8))) short short8;
typedef __attribute__((ext_vector_type(4))) float f32x4;

static __device__ __forceinline__ float b2f(__hip_bfloat16 v) { return __bfloat162float(v); }
static __device__ __forceinline__ __hip_bfloat16 f2b(float v) { return __float2bfloat16(v); }

static __device__ __forceinline__ void store_out(float* p, float v) { *p = v; }
static __device__ __forceinline__ void store_out(__hip_bfloat16* p, float v) { *p = f2b(v); }

// packed (re,im) bf16 pair helpers: lo 16 bits = re, hi 16 bits = im
static __device__ __forceinline__ float bflo(unsigned u) { return __uint_as_float(u << 16); }
static __device__ __forceinline__ float bfhi(unsigned u) { return __uint_as_float(u & 0xffff0000u); }
static __device__ __forceinline__ unsigned packbf2(float re, float im) {
    union { __hip_bfloat16 h; unsigned short s; } a, b;
    a.h = f2b(re); b.h = f2b(im);
    return (unsigned)a.s | ((unsigned)b.s << 16);
}

// async global -> LDS, 16B per lane, dest = uniform base + lane*16
static __device__ __forceinline__ void load_lds16(const unsigned short* g, unsigned short* l) {
    __builtin_amdgcn_global_load_lds(
        (const __attribute__((address_space(1))) unsigned int*)g,
        (__attribute__((address_space(3))) unsigned int*)l, 16, 0, 0);
}

static __device__ __forceinline__ int get_start(const int* start, int mode, int t) {
    return mode ? (int)((const unsigned char*)start)[t] : start[t];
}

// ---------------------------------------------------------------------------
// prep_all: one launch for x->bf16, B1, B2, and start-dtype detection.
//   blocks [0,16384)      : xb = bf16(x), 1024 elems/block
//   blocks [16384,18432)  : B1 (1024x512) row 2h=B_re[h,:]*e^g, 2h+1=B_im[h,:]*e^g
//   blocks [18432,20480)  : B2 (512x1024) col 2h=C_re[m,h], 2h+1=-C_im[m,h]
//   block  20480          : detect start dtype (int32 0/1 never reads >1 as u32;
//                           byte-packed bools ~50% density certainly do)
// ---------------------------------------------------------------------------
__global__ void prep_all(const float* __restrict__ x,
                         const float* __restrict__ B_re,
                         const float* __restrict__ B_im,
                         const float* __restrict__ gamma_log,
                         const float* __restrict__ C_re,
                         const float* __restrict__ C_im,
                         const unsigned* __restrict__ startw,
                         __hip_bfloat16* __restrict__ xb,
                         __hip_bfloat16* __restrict__ B1,
                         __hip_bfloat16* __restrict__ B2,
                         int* __restrict__ smode) {
    int b = blockIdx.x;
    if (b < 16384) {
        int i = (b * 256 + threadIdx.x) * 4;
        float4 v = *(const float4*)(x + i);
        xb[i + 0] = f2b(v.x);
        xb[i + 1] = f2b(v.y);
        xb[i + 2] = f2b(v.z);
        xb[i + 3] = f2b(v.w);
    } else if (b < 18432) {
        int idx = (b - 16384) * 256 + threadIdx.x;   // 0 .. 1024*512-1
        int row = idx >> 9;
        int m   = idx & 511;
        int h   = row >> 1;
        float g = expf(gamma_log[h]);
        float v = (row & 1) ? B_im[(size_t)h * 512 + m] : B_re[(size_t)h * 512 + m];
        B1[idx] = f2b(v * g);
    } else if (b < 20480) {
        int idx = (b - 18432) * 256 + threadIdx.x;   // 0 .. 512*1024-1
        int m = idx >> 10;
        int k = idx & 1023;
        int h = k >> 1;
        float v = (k & 1) ? -C_im[(size_t)m * 512 + h]
                          :  C_re[(size_t)m * 512 + h];
        B2[idx] = f2b(v);
    } else if (threadIdx.x < 64) {
        int v = 0;
        for (int i = threadIdx.x; i < 8192; i += 64) v |= (startw[i] > 1u) ? 1 : 0;
        unsigned long long bal = __ballot(v);
        if (threadIdx.x == 0) *smode = (bal != 0ull) ? 1 : 0;
    }
}

// ---------------------------------------------------------------------------
// GEMM: Out[m][n] = sum_k A[m][k] * B[n][k]   (A: M x K, B: N x K, bf16)
// 128x128 tile, BK=64, 4 waves, mfma_f32_16x16x32_bf16, global_load_lds staging.
// Grid: blockIdx.x = M-tile (fast dim) so N-tiles sharing an A-row-tile land on
// the same XCD (linear id differs by gridDim.x -> same id%8) -> A-tile served
// from that XCD's L2.
// optional epilogue: + xres[m][n] * Dv[n]  (xres bf16, Dv fp32; used by GEMM2)
// ---------------------------------------------------------------------------
template <int KDIM, typename OutT>
__global__ void gemm_bt(const __hip_bfloat16* __restrict__ A,
                        const __hip_bfloat16* __restrict__ B,
                        OutT* __restrict__ out, int ldc,
                        const __hip_bfloat16* __restrict__ xres,
                        const float* __restrict__ Dv) {
    __shared__ unsigned short As[128 * 64];
    __shared__ unsigned short Bs[128 * 64];
    const int lane = threadIdx.x & 63;
    const int wave = threadIdx.x >> 6;
    const int by = blockIdx.x;          // row tile (M/128)  -- fast dim
    const int bx = blockIdx.y;          // col tile (N/128)
    const int wm = (wave >> 1) * 64;
    const int wn = (wave & 1) * 64;
    const int lrow = lane >> 3;         // 0..7
    const int lcol = (lane & 7) * 8;    // 0..56

    const unsigned short* Au = (const unsigned short*)A;
    const unsigned short* Bu = (const unsigned short*)B;

    f32x4 acc[4][4] = {};

    for (int kt = 0; kt < KDIM / 64; ++kt) {
        const int k0 = kt * 64;
#pragma unroll
        for (int j = 0; j < 4; ++j) {
            int ii = wave * 4 + j;              // 0..15, 8 rows per instruction
            int row = ii * 8 + lrow;
            load_lds16(Au + (size_t)(by * 128 + row) * KDIM + k0 + lcol, &As[ii * 512]);
            load_lds16(Bu + (size_t)(bx * 128 + row) * KDIM + k0 + lcol, &Bs[ii * 512]);
        }
        __syncthreads();
#pragma unroll
        for (int ks = 0; ks < 2; ++ks) {
            short8 af[4], bfr[4];
#pragma unroll
            for (int i = 0; i < 4; ++i) {
                af[i]  = *(const short8*)&As[(wm + i * 16 + (lane & 15)) * 64 + ks * 32 + (lane >> 4) * 8];
                bfr[i] = *(const short8*)&Bs[(wn + i * 16 + (lane & 15)) * 64 + ks * 32 + (lane >> 4) * 8];
            }
#pragma unroll
            for (int i = 0; i < 4; ++i)
#pragma unroll
                for (int j = 0; j < 4; ++j)
                    acc[i][j] = __builtin_amdgcn_mfma_f32_16x16x32_bf16(af[i], bfr[j], acc[i][j], 0, 0, 0);
        }
        __syncthreads();
    }

    // epilogue: C/D layout col=lane&15, row=(lane>>4)*4+r
    const int rowq = (lane >> 4) * 4;
#pragma unroll
    for (int i = 0; i < 4; ++i) {
#pragma unroll
        for (int r = 0; r < 4; ++r) {
            int row = by * 128 + wm + i * 16 + rowq + r;
#pragma unroll
            for (int j = 0; j < 4; ++j) {
                int col = bx * 128 + wn + j * 16 + (lane & 15);
                float v = acc[i][j][r];
                if (xres) v += b2f(xres[(size_t)row * DM + col]) * Dv[col];
                store_out(&out[(size_t)row * ldc + col], v);
            }
        }
    }
}

// ---------------------------------------------------------------------------
// Segmented scan, 3 phases. Bu layout: row t = 512 packed uints, uint h =
// (re,im) bf16 pair of channel h.  h_t = lambda*(start_t?0:h_{t-1}) + Bu_t.
// Phase 3 overwrites Bu in place with xs (same interleaved layout).
// Loads are issued in batches of 8 ahead of the recurrence/stores so the
// compiler is not blocked by in-place may-alias ordering.
// ---------------------------------------------------------------------------
static __device__ __forceinline__ void get_lambda(const float* nu_log,
                                                  const float* theta_log,
                                                  int h, float& lr, float& li) {
    float nu = expf(nu_log[h]);
    float th = expf(theta_log[h]);
    float mag = expf(-nu);
    lr = mag * cosf(th);
    li = mag * sinf(th);
}

__global__ void scan_phase1(const unsigned* __restrict__ Bu,
                            const int* __restrict__ start,
                            const int* __restrict__ smode,
                            const float* __restrict__ nu_log,
                            const float* __restrict__ theta_log,
                            float4* __restrict__ agg) {
    const int h = threadIdx.x;      // 0..511
    const int c = blockIdx.x;       // 0..NC-1
    const int mode = *smode;
    float lr, li;
    get_lambda(nu_log, theta_log, h, lr, li);
    float ar = 1.f, ai = 0.f, br = 0.f, bi = 0.f;
    const int t0 = c * CL;
    for (int i0 = 0; i0 < CL; i0 += 8) {
        unsigned uu[8]; int ss[8];
#pragma unroll
        for (int k = 0; k < 8; ++k) {
            int t = t0 + i0 + k;
            uu[k] = Bu[(size_t)t * 512 + h];
            ss[k] = get_start(start, mode, t);
        }
#pragma unroll
        for (int k = 0; k < 8; ++k) {
            float s = ss[k] ? 0.f : 1.f;
            float slr = lr * s, sli = li * s;
            float bur = bflo(uu[k]), bui = bfhi(uu[k]);
            float nar = slr * ar - sli * ai;
            float nai = slr * ai + sli * ar;
            float nbr = slr * br - sli * bi + bur;
            float nbi = slr * bi + sli * br + bui;
            ar = nar; ai = nai; br = nbr; bi = nbi;
        }
    }
    agg[(size_t)c * DH + h] = make_float4(ar, ai, br, bi);
}

__global__ void scan_phase2(const float4* __restrict__ agg,
                            const float* __restrict__ state,
                            float2* __restrict__ prefix) {
    const int h = threadIdx.x;      // 0..511
    float hr = state[h];
    float hi = 0.f;
#pragma unroll 8
    for (int c = 0; c < NC; ++c) {
        prefix[(size_t)c * DH + h] = make_float2(hr, hi);
        float4 a = agg[(size_t)c * DH + h];
        float nr = a.x * hr - a.y * hi + a.z;
        float ni = a.x * hi + a.y * hr + a.w;
        hr = nr; hi = ni;
    }
}

__global__ void scan_phase3(unsigned* __restrict__ Bu,   // in: Bu, out: xs (in place)
                            const int* __restrict__ start,
                            const int* __restrict__ smode,
                            const float* __restrict__ nu_log,
                            const float* __restrict__ theta_log,
                            const float2* __restrict__ prefix,
                            float* __restrict__ dstate, int interleaved) {
    const int h = threadIdx.x;
    const int c = blockIdx.x;
    const int mode = *smode;
    float lr, li;
    get_lambda(nu_log, theta_log, h, lr, li);
    float2 p = prefix[(size_t)c * DH + h];
    float hr = p.x, hi = p.y;
    const int t0 = c * CL;
    for (int i0 = 0; i0 < CL; i0 += 8) {
        unsigned uu[8]; int ss[8];
#pragma unroll
        for (int k = 0; k < 8; ++k) {
            int t = t0 + i0 + k;
            uu[k] = Bu[(size_t)t * 512 + h];
            ss[k] = get_start(start, mode, t);
        }
#pragma unroll
        for (int k = 0; k < 8; ++k) {
            float s = ss[k] ? 0.f : 1.f;
            float slr = lr * s, sli = li * s;
            float bur = bflo(uu[k]), bui = bfhi(uu[k]);
            float nhr = slr * hr - sli * hi + bur;
            float nhi = slr * hi + sli * hr + bui;
            hr = nhr; hi = nhi;
            Bu[(size_t)(t0 + i0 + k) * 512 + h] = packbf2(hr, hi);
        }
    }
    if (c == NC - 1) {              // final state
        if (interleaved) {          // complex64 flat view: (re, im) pairs
            dstate[2 * h]     = hr;
            dstate[2 * h + 1] = hi;
        } else {                    // unsafe-cast to fp32: real part only
            dstate[h] = hr;
        }
    }
}

// ---------------------------------------------------------------------------
extern "C" void kernel_launch(void* const* d_in, const int* in_sizes, int n_in,
                              void* d_out, int out_size, void* d_ws, size_t ws_size,
                              hipStream_t stream) {
    const float* state = (const float*)d_in[0];
    const float* x     = (const float*)d_in[1];
    const int*   start = (const int*)d_in[2];
    const float* theta = (const float*)d_in[3];
    const float* nu    = (const float*)d_in[4];
    const float* gam   = (const float*)d_in[5];
    const float* B_re  = (const float*)d_in[6];
    const float* B_im  = (const float*)d_in[7];
    const float* C_re  = (const float*)d_in[8];
    const float* C_im  = (const float*)d_in[9];
    const float* Dv    = (const float*)d_in[10];
    float* out = (float*)d_out;

    const long long t_dm = (long long)T_LEN * DM;
    int state_floats = (int)((long long)out_size - t_dm);
    int interleaved = (state_floats >= 1024) ? 1 : 0;
    if (state_floats < 512) state_floats = 512;   // safety fallback

    // workspace layout (~104 MB total)
    char* ws = (char*)d_ws;
    __hip_bfloat16* xb = (__hip_bfloat16*)(ws);                     // 32 MB (T x 512 bf16)
    __hip_bfloat16* B1 = (__hip_bfloat16*)(ws + (32ll << 20));      // 1 MB  (1024x512)
    __hip_bfloat16* B2 = (__hip_bfloat16*)(ws + (33ll << 20));      // 1 MB  (512x1024)
    __hip_bfloat16* Bu = (__hip_bfloat16*)(ws + (34ll << 20));      // 64 MB (T x 1024), becomes xs in place
    float4* agg        = (float4*)(ws + (98ll << 20));              // 4 MB  (NC x 512 x 16B)
    float2* pre        = (float2*)(ws + (102ll << 20));             // 2 MB  (NC x 512 x 8B)
    int* smode         = (int*)(ws + (104ll << 20));                // 4 B

    prep_all<<<20481, 256, 0, stream>>>(x, B_re, B_im, gam, C_re, C_im,
                                        (const unsigned*)start, xb, B1, B2, smode);
    // GEMM1: Bu = xb @ B1^T   (M=32768, N=1024, K=512), by fast for XCD/L2 reuse
    gemm_bt<512, __hip_bfloat16><<<dim3(256, 8), 256, 0, stream>>>(xb, B1, Bu, 1024, nullptr, nullptr);
    scan_phase1<<<NC, 512, 0, stream>>>((const unsigned*)Bu, start, smode, nu, theta, agg);
    scan_phase2<<<1, 512, 0, stream>>>(agg, state, pre);
    scan_phase3<<<NC, 512, 0, stream>>>((unsigned*)Bu, start, smode, nu, theta, pre, out, interleaved);
    // GEMM2: outputs = xs @ B2^T + x*D   (M=32768, N=512, K=1024), fp32 out
    gemm_bt<1024, float><<<dim3(256, 4), 256, 0, stream>>>(Bu, B2, out + state_floats, 512, xb, Dv);
}

// Round 7
// 301.488 us; speedup vs baseline: 1.3111x; 1.1897x over previous
//
#include <hip/hip_runtime.h>
#include <hip/hip_bf16.h>
#include <stdint.h>

#define T_LEN 32768
#define DM 512
#define DH 512
#define NC 512          // number of scan chunks
#define CL 64           // chunk length  (NC*CL == T_LEN)

typedef __attribute__((ext_vector_type(8))) short short8;
typedef __attribute__((ext_vector_type(4))) float f32x4;

static __device__ __forceinline__ float b2f(__hip_bfloat16 v) { return __bfloat162float(v); }
static __device__ __forceinline__ __hip_bfloat16 f2b(float v) { return __float2bfloat16(v); }

static __device__ __forceinline__ void store_out(float* p, float v) { *p = v; }
static __device__ __forceinline__ void store_out(__hip_bfloat16* p, float v) { *p = f2b(v); }

// packed (re,im) bf16 pair helpers: lo 16 bits = re, hi 16 bits = im
static __device__ __forceinline__ float bflo(unsigned u) { return __uint_as_float(u << 16); }
static __device__ __forceinline__ float bfhi(unsigned u) { return __uint_as_float(u & 0xffff0000u); }
static __device__ __forceinline__ unsigned packbf2(float re, float im) {
    union { __hip_bfloat16 h; unsigned short s; } a, b;
    a.h = f2b(re); b.h = f2b(im);
    return (unsigned)a.s | ((unsigned)b.s << 16);
}

// async global -> LDS, 16B per lane, dest = uniform base + lane*16
static __device__ __forceinline__ void load_lds16(const unsigned short* g, unsigned short* l) {
    __builtin_amdgcn_global_load_lds(
        (const __attribute__((address_space(1))) unsigned int*)g,
        (__attribute__((address_space(3))) unsigned int*)l, 16, 0, 0);
}

static __device__ __forceinline__ int get_start(const int* start, int mode, int t) {
    return mode ? (int)((const unsigned char*)start)[t] : start[t];
}

// ---------------------------------------------------------------------------
// prep_all: one launch for x->bf16, B1, B2, and start-dtype detection.
// ---------------------------------------------------------------------------
__global__ void prep_all(const float* __restrict__ x,
                         const float* __restrict__ B_re,
                         const float* __restrict__ B_im,
                         const float* __restrict__ gamma_log,
                         const float* __restrict__ C_re,
                         const float* __restrict__ C_im,
                         const unsigned* __restrict__ startw,
                         __hip_bfloat16* __restrict__ xb,
                         __hip_bfloat16* __restrict__ B1,
                         __hip_bfloat16* __restrict__ B2,
                         int* __restrict__ smode) {
    int b = blockIdx.x;
    if (b < 16384) {
        int i = (b * 256 + threadIdx.x) * 4;
        float4 v = *(const float4*)(x + i);
        xb[i + 0] = f2b(v.x);
        xb[i + 1] = f2b(v.y);
        xb[i + 2] = f2b(v.z);
        xb[i + 3] = f2b(v.w);
    } else if (b < 18432) {
        int idx = (b - 16384) * 256 + threadIdx.x;   // 0 .. 1024*512-1
        int row = idx >> 9;
        int m   = idx & 511;
        int h   = row >> 1;
        float g = expf(gamma_log[h]);
        float v = (row & 1) ? B_im[(size_t)h * 512 + m] : B_re[(size_t)h * 512 + m];
        B1[idx] = f2b(v * g);
    } else if (b < 20480) {
        int idx = (b - 18432) * 256 + threadIdx.x;   // 0 .. 512*1024-1
        int m = idx >> 10;
        int k = idx & 1023;
        int h = k >> 1;
        float v = (k & 1) ? -C_im[(size_t)m * 512 + h]
                          :  C_re[(size_t)m * 512 + h];
        B2[idx] = f2b(v);
    } else if (threadIdx.x < 64) {
        int v = 0;
        for (int i = threadIdx.x; i < 8192; i += 64) v |= (startw[i] > 1u) ? 1 : 0;
        unsigned long long bal = __ballot(v);
        if (threadIdx.x == 0) *smode = (bal != 0ull) ? 1 : 0;
    }
}

// ---------------------------------------------------------------------------
// GEMM: Out[m][n] = sum_k A[m][k] * B[n][k]   (A: M x K, B: N x K, bf16)
// 128x128 tile, BK=64, 4 waves, mfma_f32_16x16x32_bf16, global_load_lds staging.
// blockIdx.x = M-tile (fast dim) -> N-tiles sharing an A-row-tile on same XCD.
// ---------------------------------------------------------------------------
template <int KDIM, typename OutT>
__global__ void gemm_bt(const __hip_bfloat16* __restrict__ A,
                        const __hip_bfloat16* __restrict__ B,
                        OutT* __restrict__ out, int ldc,
                        const __hip_bfloat16* __restrict__ xres,
                        const float* __restrict__ Dv) {
    __shared__ unsigned short As[128 * 64];
    __shared__ unsigned short Bs[128 * 64];
    const int lane = threadIdx.x & 63;
    const int wave = threadIdx.x >> 6;
    const int by = blockIdx.x;          // row tile (M/128)  -- fast dim
    const int bx = blockIdx.y;          // col tile (N/128)
    const int wm = (wave >> 1) * 64;
    const int wn = (wave & 1) * 64;
    const int lrow = lane >> 3;         // 0..7
    const int lcol = (lane & 7) * 8;    // 0..56

    const unsigned short* Au = (const unsigned short*)A;
    const unsigned short* Bu = (const unsigned short*)B;

    f32x4 acc[4][4] = {};

    for (int kt = 0; kt < KDIM / 64; ++kt) {
        const int k0 = kt * 64;
#pragma unroll
        for (int j = 0; j < 4; ++j) {
            int ii = wave * 4 + j;              // 0..15, 8 rows per instruction
            int row = ii * 8 + lrow;
            load_lds16(Au + (size_t)(by * 128 + row) * KDIM + k0 + lcol, &As[ii * 512]);
            load_lds16(Bu + (size_t)(bx * 128 + row) * KDIM + k0 + lcol, &Bs[ii * 512]);
        }
        __syncthreads();
#pragma unroll
        for (int ks = 0; ks < 2; ++ks) {
            short8 af[4], bfr[4];
#pragma unroll
            for (int i = 0; i < 4; ++i) {
                af[i]  = *(const short8*)&As[(wm + i * 16 + (lane & 15)) * 64 + ks * 32 + (lane >> 4) * 8];
                bfr[i] = *(const short8*)&Bs[(wn + i * 16 + (lane & 15)) * 64 + ks * 32 + (lane >> 4) * 8];
            }
#pragma unroll
            for (int i = 0; i < 4; ++i)
#pragma unroll
                for (int j = 0; j < 4; ++j)
                    acc[i][j] = __builtin_amdgcn_mfma_f32_16x16x32_bf16(af[i], bfr[j], acc[i][j], 0, 0, 0);
        }
        __syncthreads();
    }

    // epilogue: C/D layout col=lane&15, row=(lane>>4)*4+r
    const int rowq = (lane >> 4) * 4;
#pragma unroll
    for (int i = 0; i < 4; ++i) {
#pragma unroll
        for (int r = 0; r < 4; ++r) {
            int row = by * 128 + wm + i * 16 + rowq + r;
#pragma unroll
            for (int j = 0; j < 4; ++j) {
                int col = bx * 128 + wn + j * 16 + (lane & 15);
                float v = acc[i][j][r];
                if (xres) v += b2f(xres[(size_t)row * DM + col]) * Dv[col];
                store_out(&out[(size_t)row * ldc + col], v);
            }
        }
    }
}

// ---------------------------------------------------------------------------
// Segmented scan. Bu layout: row t = 512 packed uints, uint h = (re,im) bf16.
// h_t = lambda*(start_t?0:h_{t-1}) + Bu_t  (complex per channel), h_{-1}=state.
// Phase 1: per-chunk affine aggregates (A,b), written TRANSPOSED aggT[h*NC+c].
// Phase 2: per-channel Kogge-Stone scan over chunk aggregates (parallel).
// Phase 3: replay inside chunk from prefix, overwrite Bu in place with xs.
// ---------------------------------------------------------------------------
static __device__ __forceinline__ void get_lambda(const float* nu_log,
                                                  const float* theta_log,
                                                  int h, float& lr, float& li) {
    float nu = expf(nu_log[h]);
    float th = expf(theta_log[h]);
    float mag = expf(-nu);
    lr = mag * cosf(th);
    li = mag * sinf(th);
}

__global__ void scan_phase1(const unsigned* __restrict__ Bu,
                            const int* __restrict__ start,
                            const int* __restrict__ smode,
                            const float* __restrict__ nu_log,
                            const float* __restrict__ theta_log,
                            float4* __restrict__ aggT) {
    const int h = threadIdx.x;      // 0..511
    const int c = blockIdx.x;       // 0..NC-1
    const int mode = *smode;
    float lr, li;
    get_lambda(nu_log, theta_log, h, lr, li);
    float ar = 1.f, ai = 0.f, br = 0.f, bi = 0.f;
    const int t0 = c * CL;
    for (int i0 = 0; i0 < CL; i0 += 8) {
        unsigned uu[8]; int ss[8];
#pragma unroll
        for (int k = 0; k < 8; ++k) {
            int t = t0 + i0 + k;
            uu[k] = Bu[(size_t)t * 512 + h];
            ss[k] = get_start(start, mode, t);
        }
#pragma unroll
        for (int k = 0; k < 8; ++k) {
            float s = ss[k] ? 0.f : 1.f;
            float slr = lr * s, sli = li * s;
            float bur = bflo(uu[k]), bui = bfhi(uu[k]);
            float nar = slr * ar - sli * ai;
            float nai = slr * ai + sli * ar;
            float nbr = slr * br - sli * bi + bur;
            float nbi = slr * bi + sli * br + bui;
            ar = nar; ai = nai; br = nbr; bi = nbi;
        }
    }
    aggT[(size_t)h * NC + c] = make_float4(ar, ai, br, bi);
}

// Parallel cross-chunk scan: one block per channel h, one thread per chunk c.
// Thread c seeds with chunk c-1's aggregate (identity at c=0); after the
// inclusive Kogge-Stone scan it holds M = compose(chunks 0..c-1) and emits
// prefix_c = A(M)*state_h + b(M).
__global__ void scan_phase2(const float4* __restrict__ aggT,
                            const float* __restrict__ state,
                            float2* __restrict__ prefix) {
    __shared__ float4 s[NC];
    const int h = blockIdx.x;       // channel
    const int c = threadIdx.x;      // chunk
    float4 v = (c == 0) ? make_float4(1.f, 0.f, 0.f, 0.f)
                        : aggT[(size_t)h * NC + (c - 1)];
    s[c] = v;
    __syncthreads();
#pragma unroll
    for (int off = 1; off < NC; off <<= 1) {
        float4 left;
        if (c >= off) left = s[c - off];
        __syncthreads();
        if (c >= off) {
            // v ∘ left : left applied first, then v
            float Ar = v.x * left.x - v.y * left.y;
            float Ai = v.x * left.y + v.y * left.x;
            float br = v.x * left.z - v.y * left.w + v.z;
            float bi = v.x * left.w + v.y * left.z + v.w;
            v = make_float4(Ar, Ai, br, bi);
            s[c] = v;
        }
        __syncthreads();
    }
    float st = state[h];
    float pr = v.x * st + v.z;
    float pi = v.y * st + v.w;
    prefix[(size_t)c * DH + h] = make_float2(pr, pi);
}

__global__ void scan_phase3(unsigned* __restrict__ Bu,   // in: Bu, out: xs (in place)
                            const int* __restrict__ start,
                            const int* __restrict__ smode,
                            const float* __restrict__ nu_log,
                            const float* __restrict__ theta_log,
                            const float2* __restrict__ prefix,
                            float* __restrict__ dstate, int interleaved) {
    const int h = threadIdx.x;
    const int c = blockIdx.x;
    const int mode = *smode;
    float lr, li;
    get_lambda(nu_log, theta_log, h, lr, li);
    float2 p = prefix[(size_t)c * DH + h];
    float hr = p.x, hi = p.y;
    const int t0 = c * CL;
    for (int i0 = 0; i0 < CL; i0 += 8) {
        unsigned uu[8]; int ss[8];
#pragma unroll
        for (int k = 0; k < 8; ++k) {
            int t = t0 + i0 + k;
            uu[k] = Bu[(size_t)t * 512 + h];
            ss[k] = get_start(start, mode, t);
        }
#pragma unroll
        for (int k = 0; k < 8; ++k) {
            float s = ss[k] ? 0.f : 1.f;
            float slr = lr * s, sli = li * s;
            float bur = bflo(uu[k]), bui = bfhi(uu[k]);
            float nhr = slr * hr - sli * hi + bur;
            float nhi = slr * hi + sli * hr + bui;
            hr = nhr; hi = nhi;
            Bu[(size_t)(t0 + i0 + k) * 512 + h] = packbf2(hr, hi);
        }
    }
    if (c == NC - 1) {              // final state
        if (interleaved) {          // complex64 flat view: (re, im) pairs
            dstate[2 * h]     = hr;
            dstate[2 * h + 1] = hi;
        } else {                    // unsafe-cast to fp32: real part only
            dstate[h] = hr;
        }
    }
}

// ---------------------------------------------------------------------------
extern "C" void kernel_launch(void* const* d_in, const int* in_sizes, int n_in,
                              void* d_out, int out_size, void* d_ws, size_t ws_size,
                              hipStream_t stream) {
    const float* state = (const float*)d_in[0];
    const float* x     = (const float*)d_in[1];
    const int*   start = (const int*)d_in[2];
    const float* theta = (const float*)d_in[3];
    const float* nu    = (const float*)d_in[4];
    const float* gam   = (const float*)d_in[5];
    const float* B_re  = (const float*)d_in[6];
    const float* B_im  = (const float*)d_in[7];
    const float* C_re  = (const float*)d_in[8];
    const float* C_im  = (const float*)d_in[9];
    const float* Dv    = (const float*)d_in[10];
    float* out = (float*)d_out;

    const long long t_dm = (long long)T_LEN * DM;
    int state_floats = (int)((long long)out_size - t_dm);
    int interleaved = (state_floats >= 1024) ? 1 : 0;
    if (state_floats < 512) state_floats = 512;   // safety fallback

    // workspace layout (~104 MB total)
    char* ws = (char*)d_ws;
    __hip_bfloat16* xb = (__hip_bfloat16*)(ws);                     // 32 MB (T x 512 bf16)
    __hip_bfloat16* B1 = (__hip_bfloat16*)(ws + (32ll << 20));      // 1 MB  (1024x512)
    __hip_bfloat16* B2 = (__hip_bfloat16*)(ws + (33ll << 20));      // 1 MB  (512x1024)
    __hip_bfloat16* Bu = (__hip_bfloat16*)(ws + (34ll << 20));      // 64 MB (T x 1024), becomes xs in place
    float4* aggT       = (float4*)(ws + (98ll << 20));              // 4 MB  (512 x NC x 16B)
    float2* pre        = (float2*)(ws + (102ll << 20));             // 2 MB  (NC x 512 x 8B)
    int* smode         = (int*)(ws + (104ll << 20));                // 4 B

    prep_all<<<20481, 256, 0, stream>>>(x, B_re, B_im, gam, C_re, C_im,
                                        (const unsigned*)start, xb, B1, B2, smode);
    // GEMM1: Bu = xb @ B1^T   (M=32768, N=1024, K=512), by fast for XCD/L2 reuse
    gemm_bt<512, __hip_bfloat16><<<dim3(256, 8), 256, 0, stream>>>(xb, B1, Bu, 1024, nullptr, nullptr);
    scan_phase1<<<NC, 512, 0, stream>>>((const unsigned*)Bu, start, smode, nu, theta, aggT);
    scan_phase2<<<512, NC, 0, stream>>>(aggT, state, pre);
    scan_phase3<<<NC, 512, 0, stream>>>((unsigned*)Bu, start, smode, nu, theta, pre, out, interleaved);
    // GEMM2: outputs = xs @ B2^T + x*D   (M=32768, N=512, K=1024), fp32 out
    gemm_bt<1024, float><<<dim3(256, 4), 256, 0, stream>>>(Bu, B2, out + state_floats, 512, xb, Dv);
}